// Round 4
// baseline (258.410 us; speedup 1.0000x reference)
//
#include <hip/hip_runtime.h>
#include <hip/hip_bf16.h>
#include <stdint.h>

// Problem constants (all inputs & output are FP32 per the reference file)
#define BATCH 128
#define LAT   2000
#define NG    10000
#define KW    20
#define OUTW  (NG * KW)   // 200000
#define EPSV  1e-5f

#define NKT   32            // 64-wide k-tiles in padded z (2048 = 32*64)
#define EG    16            // groups per block (NG = 625 * 16 exactly)
#define HR_STRIDE 132       // LDS row stride (floats): <=2-way bank alias (free)

typedef __bf16 bf16x8 __attribute__((ext_vector_type(8)));
typedef float  f32x4  __attribute__((ext_vector_type(4)));

__device__ __forceinline__ ushort f2bf(float f) {
  uint32_t u = __builtin_bit_cast(uint32_t, f);
  u = (u + 0x7FFFu + ((u >> 16) & 1u)) >> 16;  // RNE
  return (ushort)u;
}

__device__ __forceinline__ int4 pack8(const float* p) {
  float4 f0 = *(const float4*)p;
  float4 f1 = *(const float4*)(p + 4);
  int4 v;
  v.x = (int)((uint32_t)f2bf(f0.x) | ((uint32_t)f2bf(f0.y) << 16));
  v.y = (int)((uint32_t)f2bf(f0.z) | ((uint32_t)f2bf(f0.w) << 16));
  v.z = (int)((uint32_t)f2bf(f1.x) | ((uint32_t)f2bf(f1.y) << 16));
  v.w = (int)((uint32_t)f2bf(f1.z) | ((uint32_t)f2bf(f1.w) << 16));
  return v;
}

// native packed RNE f32->bf16 (compiler emits v_cvt_pk_bf16_f32 pairs)
__device__ __forceinline__ bf16x8 cvt8(float4 a, float4 b) {
  bf16x8 r;
  r[0] = (__bf16)a.x; r[1] = (__bf16)a.y; r[2] = (__bf16)a.z; r[3] = (__bf16)a.w;
  r[4] = (__bf16)b.x; r[5] = (__bf16)b.y; r[6] = (__bf16)b.z; r[7] = (__bf16)b.w;
  return r;
}

// =====================================================================
// Phase 0: z (128 x 2000 f32) -> LINEAR bf16 image [128][2048], zero-
// padded. 16-B chunk cg: row cg>>8, k-offset (cg&255)*8. The fused GEMM
// loads B-fragments directly from this image (one dwordx4 per fragment).
// =====================================================================
__global__ __launch_bounds__(256) void zprep_kernel(
    const float* __restrict__ zp, int4* __restrict__ zlin) {
  const int cg = blockIdx.x * 256 + threadIdx.x;   // 0..32767
  const int r  = cg >> 8;
  const int k0 = (cg & 255) * 8;
  int4 v = make_int4(0, 0, 0, 0);
  if (k0 < LAT) v = pack8(zp + (size_t)r * LAT + k0);  // LAT%8==0: no straddle
  zlin[cg] = v;
}

// =====================================================================
// Fused pipeline, barrier-free GEMM phase. One block = 16 groups x all
// 128 batches; 512 threads = 8 waves, wave w owns batches w*16..w*16+15.
// No LDS staging in the GEMM: z fragments come straight from the linear
// bf16 image (L2-hot, wave-private rows); W fragments are loaded f32 from
// global (the HBM stream; 8-wave redundancy merges in L1) and cvt'd in
// registers. W prefetched 2 tiles ahead, z 1 tile ahead, all in named
// registers -> waves dataflow independently, no per-iter __syncthreads.
// Then: h -> LDS -> BN stats -> store-coalesced expand (2 barriers total).
// =====================================================================
__global__ __launch_bounds__(512, 4) void fused16_kernel(
    const int4* __restrict__ zlin, const float* __restrict__ wp,
    const float* __restrict__ gammap, const float* __restrict__ betap,
    const float* __restrict__ convwp, const float* __restrict__ convbp,
    float* __restrict__ out) {
  const int tid = threadIdx.x;
  const int g0  = blockIdx.x * EG;

  __shared__ float  h_raw[EG * HR_STRIDE];   // raw (pre-BN) h
  __shared__ float4 cw_s[EG * 5];            // conv_w window
  __shared__ float  cb_s[EG];
  __shared__ float  scale_s[EG];
  __shared__ float  shift_s[EG];

  if (tid < EG * 5)
    cw_s[tid] = *(const float4*)(convwp + (size_t)g0 * KW + tid * 4);
  if (tid < EG) cb_s[tid] = convbp[g0 + tid];

  const int lane = tid & 63;
  const int w    = tid >> 6;       // wave id 0..7
  const int q    = lane >> 4;      // 0..3
  const int cl   = lane & 15;      // 0..15
  const int rb   = w * 16 + cl;    // batch row this lane feeds (B operand)

  const float* wrow = wp + (size_t)(g0 + cl) * LAT;   // A row (group g0+cl)
  const int4*  zrow = zlin + (size_t)rb * 256;        // 256 chunks per row

  f32x4 acc = {0.f, 0.f, 0.f, 0.f};

  // ---- prologue: W tiles 0,1 and z tile 0 in flight ----
  const int koq = q * 8;
  float4 a0 = *(const float4*)(wrow + koq);            // tile 0, kk=0
  float4 a1 = *(const float4*)(wrow + koq + 4);
  float4 a2 = *(const float4*)(wrow + 32 + koq);       // tile 0, kk=1
  float4 a3 = *(const float4*)(wrow + 32 + koq + 4);
  float4 b0 = *(const float4*)(wrow + 64 + koq);       // tile 1
  float4 b1 = *(const float4*)(wrow + 64 + koq + 4);
  float4 b2 = *(const float4*)(wrow + 96 + koq);
  float4 b3 = *(const float4*)(wrow + 96 + koq + 4);
  int4 zb0 = zrow[q];                                  // tile 0
  int4 zb1 = zrow[4 + q];

#pragma unroll 2
  for (int it = 0; it < NKT; ++it) {
    // issue W loads for tile it+2 (clamped; tail garbage x z-pad-zero = 0)
    const int tc = (it + 2 < NKT) ? (it + 2) : (NKT - 1);
    int kc0 = tc * 64 + koq;
    int kc1 = tc * 64 + 32 + koq;
    kc0 = (kc0 > LAT - 8) ? (LAT - 8) : kc0;
    kc1 = (kc1 > LAT - 8) ? (LAT - 8) : kc1;
    float4 c0 = *(const float4*)(wrow + kc0);
    float4 c1 = *(const float4*)(wrow + kc0 + 4);
    float4 c2 = *(const float4*)(wrow + kc1);
    float4 c3 = *(const float4*)(wrow + kc1 + 4);
    // issue z loads for tile it+1
    const int tn = (it + 1 < NKT) ? (it + 1) : (NKT - 1);
    int4 zn0 = zrow[tn * 8 + q];
    int4 zn1 = zrow[tn * 8 + 4 + q];

    // compute tile it: cvt W frags (loaded 2 iters ago), 2 MFMAs
    bf16x8 af0 = cvt8(a0, a1);
    bf16x8 af1 = cvt8(a2, a3);
    acc = __builtin_amdgcn_mfma_f32_16x16x32_bf16(
        af0, __builtin_bit_cast(bf16x8, zb0), acc, 0, 0, 0);
    acc = __builtin_amdgcn_mfma_f32_16x16x32_bf16(
        af1, __builtin_bit_cast(bf16x8, zb1), acc, 0, 0, 0);

    // rotate pipeline registers (SSA, no arrays)
    a0 = b0; a1 = b1; a2 = b2; a3 = b3;
    b0 = c0; b1 = c1; b2 = c2; b3 = c3;
    zb0 = zn0; zb1 = zn1;
  }

  // ---- h -> LDS (D layout: row q*4+r = local group, col = batch rb) ----
#pragma unroll
  for (int r = 0; r < 4; ++r)
    h_raw[(q * 4 + r) * HR_STRIDE + rb] = acc[r];
  __syncthreads();

  // ---- BN stats: 512 threads = 16 groups x 32 batch-quads ----
  {
    const int gl = tid >> 5;                 // local group 0..15
    const int bb = (tid & 31) * 4;           // batch base 0..124
    const float4 a = *(const float4*)&h_raw[gl * HR_STRIDE + bb];
    float sm = a.x + a.y + a.z + a.w;
    float sq = a.x * a.x + a.y * a.y + a.z * a.z + a.w * a.w;
#pragma unroll
    for (int m = 1; m < 32; m <<= 1) {
      sm += __shfl_xor(sm, m);
      sq += __shfl_xor(sq, m);
    }
    if ((tid & 31) == 0) {
      float mean = sm * (1.f / 128.f);
      float var  = sq * (1.f / 128.f) - mean * mean;
      var = (var < 0.f) ? 0.f : var;
      float inv   = __builtin_amdgcn_rsqf(var + EPSV);
      float scale = inv * gammap[g0 + gl];
      scale_s[gl] = scale;
      shift_s[gl] = betap[g0 + gl] - mean * scale;
    }
  }
  __syncthreads();

  // ---- expansion: 480 threads = 6 batch rows x 80 float4 columns.
  // A wave's store covers 1024 contiguous output bytes. ----
  if (tid < 480) {
    const int col4 = tid % 80;           // float4 column in 1280-B window row
    const int r0   = tid / 80;           // 0..5
    const int gl   = col4 / 5;           // local group of this column
    const float4 w4  = cw_s[col4];
    const float  cb  = cb_s[gl];
    const float  scl = scale_s[gl];
    const float  sft = shift_s[gl];
    const float* hsrc = &h_raw[gl * HR_STRIDE];
    float* obase = out + (size_t)g0 * KW + (size_t)col4 * 4;
    for (int j = 0; j < 22; ++j) {       // ceil(128/6) passes
      const int row = j * 6 + r0;        // batch index
      if (row < BATCH) {
        float h = hsrc[row];
        h = fmaf(h, scl, sft);
        h = fmaxf(h, h * 0.1f);          // leaky(0.1)
        float y0 = fmaf(h, w4.x, cb);
        float y1 = fmaf(h, w4.y, cb);
        float y2 = fmaf(h, w4.z, cb);
        float y3 = fmaf(h, w4.w, cb);
        y0 = fmaxf(y0, y0 * 0.1f);
        y1 = fmaxf(y1, y1 * 0.1f);
        y2 = fmaxf(y2, y2 * 0.1f);
        y3 = fmaxf(y3, y3 * 0.1f);
        float4 ov;
        ov.x = __builtin_amdgcn_rcpf(1.f + exp2f(y0 * -1.44269504f));
        ov.y = __builtin_amdgcn_rcpf(1.f + exp2f(y1 * -1.44269504f));
        ov.z = __builtin_amdgcn_rcpf(1.f + exp2f(y2 * -1.44269504f));
        ov.w = __builtin_amdgcn_rcpf(1.f + exp2f(y3 * -1.44269504f));
        *(float4*)(obase + (size_t)row * OUTW) = ov;
      }
    }
  }
}

// =====================================================================
// Fallback: fused kernel (used only if ws is too small). Reads z directly.
// =====================================================================
#define BKF 64
__global__ __launch_bounds__(256, 2) void fused_decoder_kernel(
    const float* __restrict__ zp, const float* __restrict__ wp,
    const float* __restrict__ gammap, const float* __restrict__ betap,
    const float* __restrict__ convwp, const float* __restrict__ convbp,
    float* __restrict__ out) {
  const int tid = threadIdx.x;
  const int g0  = blockIdx.x * 32;

  __shared__ ushort As[BATCH * BKF];
  __shared__ ushort Bs[32 * BKF];
  __shared__ float statS[2][2][16];
  __shared__ float statQ[2][2][16];

  const int lane = tid & 63;
  const int w    = tid >> 6;
  const int wm   = w & 1;
  const int wn   = w >> 1;
  const int q    = lane >> 4;
  const int cl   = lane & 15;

  f32x4 acc[4];
  const f32x4 vzero = {0.f, 0.f, 0.f, 0.f};
#pragma unroll
  for (int i = 0; i < 4; ++i) acc[i] = vzero;

  for (int it = 0; it < 32; ++it) {
    const int k0 = it * BKF;
    __syncthreads();
#pragma unroll
    for (int i = 0; i < 4; ++i) {
      int c = i * 256 + tid;
      int r = c >> 3, sc = c & 7;
      int gk = k0 + sc * 8;
      int4 v = make_int4(0, 0, 0, 0);
      if (gk < LAT) v = pack8(zp + (size_t)r * LAT + gk);
      *(int4*)&As[r * BKF + ((sc ^ (r & 7)) << 3)] = v;
    }
    {
      int r = tid >> 3, sc = tid & 7;
      int g  = g0 + r;
      int gk = k0 + sc * 8;
      int4 v = make_int4(0, 0, 0, 0);
      if (gk < LAT && g < NG) v = pack8(wp + (size_t)g * LAT + gk);
      *(int4*)&Bs[r * BKF + ((sc ^ (r & 7)) << 3)] = v;
    }
    __syncthreads();
#pragma unroll
    for (int kk = 0; kk < 2; ++kk) {
      int sc = kk * 4 + q;
      bf16x8 af[4], bfr;
#pragma unroll
      for (int mt = 0; mt < 4; ++mt) {
        int ra = wm * 64 + mt * 16 + cl;
        af[mt] = *(const bf16x8*)&As[ra * BKF + ((sc ^ (ra & 7)) << 3)];
      }
      {
        int rbx = wn * 16 + cl;
        bfr = *(const bf16x8*)&Bs[rbx * BKF + ((sc ^ (rbx & 7)) << 3)];
      }
#pragma unroll
      for (int mt = 0; mt < 4; ++mt)
        acc[mt] = __builtin_amdgcn_mfma_f32_16x16x32_bf16(af[mt], bfr,
                                                          acc[mt], 0, 0, 0);
    }
  }

  float s = 0.f, ss = 0.f;
#pragma unroll
  for (int mt = 0; mt < 4; ++mt)
#pragma unroll
    for (int r = 0; r < 4; ++r) {
      float v = acc[mt][r];
      s += v; ss += v * v;
    }
  s += __shfl_xor(s, 16); ss += __shfl_xor(ss, 16);
  s += __shfl_xor(s, 32); ss += __shfl_xor(ss, 32);
  if (q == 0) { statS[wm][wn][cl] = s; statQ[wm][wn][cl] = ss; }
  __syncthreads();

  const int gcol = g0 + wn * 16 + cl;
  const int gc   = (gcol < NG) ? gcol : (NG - 1);
  float S = statS[0][wn][cl] + statS[1][wn][cl];
  float Q = statQ[0][wn][cl] + statQ[1][wn][cl];
  float mean = S * (1.f / 128.f);
  float var  = Q * (1.f / 128.f) - mean * mean;
  var = (var < 0.f) ? 0.f : var;
  float inv = __builtin_amdgcn_rsqf(var + EPSV);
  float ga = gammap[gc], be = betap[gc], cb = convbp[gc];
  float wv[KW];
  {
    const float4* pw = (const float4*)(convwp + (size_t)gc * KW);
#pragma unroll
    for (int j = 0; j < 5; ++j) {
      float4 f = pw[j];
      wv[4 * j] = f.x; wv[4 * j + 1] = f.y;
      wv[4 * j + 2] = f.z; wv[4 * j + 3] = f.w;
    }
  }
  float scale = inv * ga;
  float shift = be - mean * scale;
  const bool ok = (gcol < NG);
#pragma unroll
  for (int mt = 0; mt < 4; ++mt) {
#pragma unroll
    for (int r = 0; r < 4; ++r) {
      float h = acc[mt][r] * scale + shift;
      h = fmaxf(h, h * 0.1f);
      int b = wm * 64 + mt * 16 + q * 4 + r;
      float4 ov[5];
#pragma unroll
      for (int j = 0; j < 5; ++j) {
        float y0 = h * wv[4 * j]     + cb;
        float y1 = h * wv[4 * j + 1] + cb;
        float y2 = h * wv[4 * j + 2] + cb;
        float y3 = h * wv[4 * j + 3] + cb;
        y0 = fmaxf(y0, y0 * 0.1f);
        y1 = fmaxf(y1, y1 * 0.1f);
        y2 = fmaxf(y2, y2 * 0.1f);
        y3 = fmaxf(y3, y3 * 0.1f);
        ov[j].x = __builtin_amdgcn_rcpf(1.f + exp2f(y0 * -1.44269504f));
        ov[j].y = __builtin_amdgcn_rcpf(1.f + exp2f(y1 * -1.44269504f));
        ov[j].z = __builtin_amdgcn_rcpf(1.f + exp2f(y2 * -1.44269504f));
        ov[j].w = __builtin_amdgcn_rcpf(1.f + exp2f(y3 * -1.44269504f));
      }
      if (ok) {
        float4* po = (float4*)(out + (size_t)b * OUTW + (size_t)gcol * KW);
#pragma unroll
        for (int j = 0; j < 5; ++j) po[j] = ov[j];
      }
    }
  }
}

extern "C" void kernel_launch(void* const* d_in, const int* in_sizes, int n_in,
                              void* d_out, int out_size, void* d_ws, size_t ws_size,
                              hipStream_t stream) {
  const float* z     = (const float*)d_in[0];
  const float* W     = (const float*)d_in[1];
  // d_in[2] = b_fc: unused — cancels under training-mode batchnorm
  const float* gamma = (const float*)d_in[3];
  const float* beta  = (const float*)d_in[4];
  const float* convw = (const float*)d_in[5];
  const float* convb = (const float*)d_in[6];
  float* out = (float*)d_out;

  const size_t zlin_bytes = (size_t)BATCH * 256 * 16;   // 512 KB

  if (ws_size >= zlin_bytes) {
    int4* zlin = (int4*)d_ws;
    zprep_kernel<<<128, 256, 0, stream>>>(z, zlin);     // 32768 chunks
    fused16_kernel<<<NG / EG, 512, 0, stream>>>(zlin, W, gamma, beta,
                                                convw, convb, out);
  } else {
    fused_decoder_kernel<<<(NG + 31) / 32, 256, 0, stream>>>(
        z, W, gamma, beta, convw, convb, out);
  }
}

// Round 5
// 201.374 us; speedup vs baseline: 1.2832x; 1.2832x over previous
//
#include <hip/hip_runtime.h>
#include <hip/hip_bf16.h>
#include <stdint.h>

// Problem constants (all inputs & output are FP32 per the reference file)
#define BATCH 128
#define LAT   2000
#define NG    10000
#define KW    20
#define OUTW  (NG * KW)   // 200000
#define EPSV  1e-5f

#define NKT   32            // 64-wide k-tiles in padded z/W (2048 = 32*64)
#define EG    16            // groups per block (NG = 625 * 16 exactly)
#define WROW  2048          // W LDS row stride (bf16 elems)
#define HR_STRIDE 132       // h LDS row stride (floats): <=2-way bank alias

typedef __bf16 bf16x8 __attribute__((ext_vector_type(8)));
typedef float  f32x4  __attribute__((ext_vector_type(4)));

__device__ __forceinline__ ushort f2bf(float f) {
  uint32_t u = __builtin_bit_cast(uint32_t, f);
  u = (u + 0x7FFFu + ((u >> 16) & 1u)) >> 16;  // RNE
  return (ushort)u;
}

__device__ __forceinline__ int4 pack8(const float* p) {
  float4 f0 = *(const float4*)p;
  float4 f1 = *(const float4*)(p + 4);
  int4 v;
  v.x = (int)((uint32_t)f2bf(f0.x) | ((uint32_t)f2bf(f0.y) << 16));
  v.y = (int)((uint32_t)f2bf(f0.z) | ((uint32_t)f2bf(f0.w) << 16));
  v.z = (int)((uint32_t)f2bf(f1.x) | ((uint32_t)f2bf(f1.y) << 16));
  v.w = (int)((uint32_t)f2bf(f1.z) | ((uint32_t)f2bf(f1.w) << 16));
  return v;
}

// =====================================================================
// Phase 0: z (128 x 2000 f32) -> bf16 image permuted to WAVE-COALESCED
// fragment order: chunk index ((kt*2+kk)*8 + wave)*64 + q*16 + cl holds
// z[wave*16+cl][kt*64 + kk*32 + q*8 .. +8]. In the GEMM, a wave's 64
// lanes (lane = q*16+cl) read 64 CONSECUTIVE chunks -> 1 KB coalesced.
// Reads here are fully coalesced; writes scatter (fire-and-forget).
// =====================================================================
__global__ __launch_bounds__(256) void zprep_kernel(
    const float* __restrict__ zp, int4* __restrict__ zlin) {
  const int cg = blockIdx.x * 256 + threadIdx.x;   // 0..32767
  const int r  = cg >> 8;        // batch row 0..127
  const int ck = cg & 255;       // 16B chunk in row; k0 = ck*8
  const int k0 = ck * 8;
  int4 v = make_int4(0, 0, 0, 0);
  if (k0 < LAT) v = pack8(zp + (size_t)r * LAT + k0);  // LAT%8==0: no straddle
  const int kt = ck >> 3, kk = (ck >> 2) & 1, q = ck & 3;
  const int dst = ((kt * 2 + kk) * 8 + (r >> 4)) * 64 + q * 16 + (r & 15);
  zlin[dst] = v;
}

// =====================================================================
// Fused pipeline. One block = 16 groups x all 128 batches; 512 threads =
// 8 waves, wave w owns batches w*16..w*16+15.
//   Stage 1 (once): ALL of W's 16 rows (128 KB f32, coalesced) -> 64 KB
//     swizzled bf16 LDS image. One barrier.
//   Stage 2 (k-loop, NO barriers, NO cvt): 32 tiles x 2 MFMAs; A-frag
//     from LDS (ds_read_b128, <=2-way), B-frag direct from the permuted
//     z image (64 consecutive chunks per wave = coalesced L2 hit).
//     16 waves/CU of pure dataflow hide all latency.
//   Stage 3: h -> LDS -> BN stats -> store-coalesced expand (2 barriers).
// =====================================================================
__global__ __launch_bounds__(512, 2) void fused16_kernel(
    const int4* __restrict__ zlin, const float* __restrict__ wp,
    const float* __restrict__ gammap, const float* __restrict__ betap,
    const float* __restrict__ convwp, const float* __restrict__ convbp,
    float* __restrict__ out) {
  const int tid = threadIdx.x;
  const int g0  = blockIdx.x * EG;

  __shared__ __attribute__((aligned(16))) ushort Wl[EG * WROW];  // 64 KB
  __shared__ float  h_raw[EG * HR_STRIDE];   // raw (pre-BN) h
  __shared__ float4 cw_s[EG * 5];            // conv_w window
  __shared__ float  cb_s[EG];
  __shared__ float  scale_s[EG];
  __shared__ float  shift_s[EG];

  if (tid < EG * 5)
    cw_s[tid] = *(const float4*)(convwp + (size_t)g0 * KW + tid * 4);
  if (tid < EG) cb_s[tid] = convbp[g0 + tid];

  // ---- stage ALL W rows for this block: 4096 16B-chunks, 8/thread.
  // Consecutive tids read contiguous 32B f32 segments (coalesced).
  // LDS layout: row*WROW + kt*64 + ((j ^ (row&7))<<3)  (per-tile XOR). ----
#pragma unroll
  for (int i = 0; i < 8; ++i) {
    int cc  = i * 512 + tid;     // 0..4095
    int row = cc >> 8;           // local group 0..15
    int c   = cc & 255;          // chunk in row
    int kt  = c >> 3, j = c & 7;
    int k0  = kt * 64 + j * 8;
    int4 v  = make_int4(0, 0, 0, 0);
    if (k0 < LAT) v = pack8(wp + (size_t)(g0 + row) * LAT + k0);
    *(int4*)&Wl[row * WROW + kt * 64 + ((j ^ (row & 7)) << 3)] = v;
  }
  __syncthreads();

  const int lane = tid & 63;
  const int w    = tid >> 6;       // wave id 0..7
  const int q    = lane >> 4;      // 0..3 (k-quarter)
  const int cl   = lane & 15;      // 0..15
  const int rb   = w * 16 + cl;    // batch row this lane feeds (B operand)

  // per-lane fragment addresses
  const int4* zw  = zlin + (size_t)w * 64 + lane;          // stride 512/kk
  const int aoff0 = cl * WROW + ((q       ^ (cl & 7)) << 3);  // kk=0 (j=q)
  const int aoff1 = cl * WROW + (((4 + q) ^ (cl & 7)) << 3);  // kk=1 (j=4+q)

  f32x4 acc = {0.f, 0.f, 0.f, 0.f};

  // ---- barrier-free k-loop: 32 tiles x (2 z loads + 2 ds_read + 2 MFMA)
#pragma unroll 4
  for (int kt = 0; kt < NKT; ++kt) {
    int4 z0 = zw[(size_t)(kt * 2 + 0) * 512];
    int4 z1 = zw[(size_t)(kt * 2 + 1) * 512];
    bf16x8 a0 = *(const bf16x8*)&Wl[aoff0 + kt * 64];
    bf16x8 a1 = *(const bf16x8*)&Wl[aoff1 + kt * 64];
    acc = __builtin_amdgcn_mfma_f32_16x16x32_bf16(
        a0, __builtin_bit_cast(bf16x8, z0), acc, 0, 0, 0);
    acc = __builtin_amdgcn_mfma_f32_16x16x32_bf16(
        a1, __builtin_bit_cast(bf16x8, z1), acc, 0, 0, 0);
  }

  // ---- h -> LDS (D layout: row q*4+r = local group, col = batch rb) ----
#pragma unroll
  for (int r = 0; r < 4; ++r)
    h_raw[(q * 4 + r) * HR_STRIDE + rb] = acc[r];
  __syncthreads();

  // ---- BN stats: 512 threads = 16 groups x 32 batch-quads ----
  {
    const int gl = tid >> 5;                 // local group 0..15
    const int bb = (tid & 31) * 4;           // batch base 0..124
    const float4 a = *(const float4*)&h_raw[gl * HR_STRIDE + bb];
    float sm = a.x + a.y + a.z + a.w;
    float sq = a.x * a.x + a.y * a.y + a.z * a.z + a.w * a.w;
#pragma unroll
    for (int m = 1; m < 32; m <<= 1) {
      sm += __shfl_xor(sm, m);
      sq += __shfl_xor(sq, m);
    }
    if ((tid & 31) == 0) {
      float mean = sm * (1.f / 128.f);
      float var  = sq * (1.f / 128.f) - mean * mean;
      var = (var < 0.f) ? 0.f : var;
      float inv   = __builtin_amdgcn_rsqf(var + EPSV);
      float scale = inv * gammap[g0 + gl];
      scale_s[gl] = scale;
      shift_s[gl] = betap[g0 + gl] - mean * scale;
    }
  }
  __syncthreads();

  // ---- expansion: 480 threads = 6 batch rows x 80 float4 columns.
  // A wave's store covers 1024 contiguous output bytes. ----
  if (tid < 480) {
    const int col4 = tid % 80;           // float4 column in 1280-B window row
    const int r0   = tid / 80;           // 0..5
    const int gl   = col4 / 5;           // local group of this column
    const float4 w4  = cw_s[col4];
    const float  cb  = cb_s[gl];
    const float  scl = scale_s[gl];
    const float  sft = shift_s[gl];
    const float* hsrc = &h_raw[gl * HR_STRIDE];
    float* obase = out + (size_t)g0 * KW + (size_t)col4 * 4;
    for (int j = 0; j < 22; ++j) {       // ceil(128/6) passes
      const int row = j * 6 + r0;        // batch index
      if (row < BATCH) {
        float h = hsrc[row];
        h = fmaf(h, scl, sft);
        h = fmaxf(h, h * 0.1f);          // leaky(0.1)
        float y0 = fmaf(h, w4.x, cb);
        float y1 = fmaf(h, w4.y, cb);
        float y2 = fmaf(h, w4.z, cb);
        float y3 = fmaf(h, w4.w, cb);
        y0 = fmaxf(y0, y0 * 0.1f);
        y1 = fmaxf(y1, y1 * 0.1f);
        y2 = fmaxf(y2, y2 * 0.1f);
        y3 = fmaxf(y3, y3 * 0.1f);
        float4 ov;
        ov.x = __builtin_amdgcn_rcpf(1.f + exp2f(y0 * -1.44269504f));
        ov.y = __builtin_amdgcn_rcpf(1.f + exp2f(y1 * -1.44269504f));
        ov.z = __builtin_amdgcn_rcpf(1.f + exp2f(y2 * -1.44269504f));
        ov.w = __builtin_amdgcn_rcpf(1.f + exp2f(y3 * -1.44269504f));
        *(float4*)(obase + (size_t)row * OUTW) = ov;
      }
    }
  }
}

// =====================================================================
// Fallback: fused kernel (used only if ws is too small). Reads z directly.
// =====================================================================
#define BKF 64
__global__ __launch_bounds__(256, 2) void fused_decoder_kernel(
    const float* __restrict__ zp, const float* __restrict__ wp,
    const float* __restrict__ gammap, const float* __restrict__ betap,
    const float* __restrict__ convwp, const float* __restrict__ convbp,
    float* __restrict__ out) {
  const int tid = threadIdx.x;
  const int g0  = blockIdx.x * 32;

  __shared__ ushort As[BATCH * BKF];
  __shared__ ushort Bs[32 * BKF];
  __shared__ float statS[2][2][16];
  __shared__ float statQ[2][2][16];

  const int lane = tid & 63;
  const int w    = tid >> 6;
  const int wm   = w & 1;
  const int wn   = w >> 1;
  const int q    = lane >> 4;
  const int cl   = lane & 15;

  f32x4 acc[4];
  const f32x4 vzero = {0.f, 0.f, 0.f, 0.f};
#pragma unroll
  for (int i = 0; i < 4; ++i) acc[i] = vzero;

  for (int it = 0; it < 32; ++it) {
    const int k0 = it * BKF;
    __syncthreads();
#pragma unroll
    for (int i = 0; i < 4; ++i) {
      int c = i * 256 + tid;
      int r = c >> 3, sc = c & 7;
      int gk = k0 + sc * 8;
      int4 v = make_int4(0, 0, 0, 0);
      if (gk < LAT) v = pack8(zp + (size_t)r * LAT + gk);
      *(int4*)&As[r * BKF + ((sc ^ (r & 7)) << 3)] = v;
    }
    {
      int r = tid >> 3, sc = tid & 7;
      int g  = g0 + r;
      int gk = k0 + sc * 8;
      int4 v = make_int4(0, 0, 0, 0);
      if (gk < LAT && g < NG) v = pack8(wp + (size_t)g * LAT + gk);
      *(int4*)&Bs[r * BKF + ((sc ^ (r & 7)) << 3)] = v;
    }
    __syncthreads();
#pragma unroll
    for (int kk = 0; kk < 2; ++kk) {
      int sc = kk * 4 + q;
      bf16x8 af[4], bfr;
#pragma unroll
      for (int mt = 0; mt < 4; ++mt) {
        int ra = wm * 64 + mt * 16 + cl;
        af[mt] = *(const bf16x8*)&As[ra * BKF + ((sc ^ (ra & 7)) << 3)];
      }
      {
        int rbx = wn * 16 + cl;
        bfr = *(const bf16x8*)&Bs[rbx * BKF + ((sc ^ (rbx & 7)) << 3)];
      }
#pragma unroll
      for (int mt = 0; mt < 4; ++mt)
        acc[mt] = __builtin_amdgcn_mfma_f32_16x16x32_bf16(af[mt], bfr,
                                                          acc[mt], 0, 0, 0);
    }
  }

  float s = 0.f, ss = 0.f;
#pragma unroll
  for (int mt = 0; mt < 4; ++mt)
#pragma unroll
    for (int r = 0; r < 4; ++r) {
      float v = acc[mt][r];
      s += v; ss += v * v;
    }
  s += __shfl_xor(s, 16); ss += __shfl_xor(ss, 16);
  s += __shfl_xor(s, 32); ss += __shfl_xor(ss, 32);
  if (q == 0) { statS[wm][wn][cl] = s; statQ[wm][wn][cl] = ss; }
  __syncthreads();

  const int gcol = g0 + wn * 16 + cl;
  const int gc   = (gcol < NG) ? gcol : (NG - 1);
  float S = statS[0][wn][cl] + statS[1][wn][cl];
  float Q = statQ[0][wn][cl] + statQ[1][wn][cl];
  float mean = S * (1.f / 128.f);
  float var  = Q * (1.f / 128.f) - mean * mean;
  var = (var < 0.f) ? 0.f : var;
  float inv = __builtin_amdgcn_rsqf(var + EPSV);
  float ga = gammap[gc], be = betap[gc], cb = convbp[gc];
  float wv[KW];
  {
    const float4* pw = (const float4*)(convwp + (size_t)gc * KW);
#pragma unroll
    for (int j = 0; j < 5; ++j) {
      float4 f = pw[j];
      wv[4 * j] = f.x; wv[4 * j + 1] = f.y;
      wv[4 * j + 2] = f.z; wv[4 * j + 3] = f.w;
    }
  }
  float scale = inv * ga;
  float shift = be - mean * scale;
  const bool ok = (gcol < NG);
#pragma unroll
  for (int mt = 0; mt < 4; ++mt) {
#pragma unroll
    for (int r = 0; r < 4; ++r) {
      float h = acc[mt][r] * scale + shift;
      h = fmaxf(h, h * 0.1f);
      int b = wm * 64 + mt * 16 + q * 4 + r;
      float4 ov[5];
#pragma unroll
      for (int j = 0; j < 5; ++j) {
        float y0 = h * wv[4 * j]     + cb;
        float y1 = h * wv[4 * j + 1] + cb;
        float y2 = h * wv[4 * j + 2] + cb;
        float y3 = h * wv[4 * j + 3] + cb;
        y0 = fmaxf(y0, y0 * 0.1f);
        y1 = fmaxf(y1, y1 * 0.1f);
        y2 = fmaxf(y2, y2 * 0.1f);
        y3 = fmaxf(y3, y3 * 0.1f);
        ov[j].x = __builtin_amdgcn_rcpf(1.f + exp2f(y0 * -1.44269504f));
        ov[j].y = __builtin_amdgcn_rcpf(1.f + exp2f(y1 * -1.44269504f));
        ov[j].z = __builtin_amdgcn_rcpf(1.f + exp2f(y2 * -1.44269504f));
        ov[j].w = __builtin_amdgcn_rcpf(1.f + exp2f(y3 * -1.44269504f));
      }
      if (ok) {
        float4* po = (float4*)(out + (size_t)b * OUTW + (size_t)gcol * KW);
#pragma unroll
        for (int j = 0; j < 5; ++j) po[j] = ov[j];
      }
    }
  }
}

extern "C" void kernel_launch(void* const* d_in, const int* in_sizes, int n_in,
                              void* d_out, int out_size, void* d_ws, size_t ws_size,
                              hipStream_t stream) {
  const float* z     = (const float*)d_in[0];
  const float* W     = (const float*)d_in[1];
  // d_in[2] = b_fc: unused — cancels under training-mode batchnorm
  const float* gamma = (const float*)d_in[3];
  const float* beta  = (const float*)d_in[4];
  const float* convw = (const float*)d_in[5];
  const float* convb = (const float*)d_in[6];
  float* out = (float*)d_out;

  const size_t zlin_bytes = (size_t)BATCH * 256 * 16;   // 512 KB

  if (ws_size >= zlin_bytes) {
    int4* zlin = (int4*)d_ws;
    zprep_kernel<<<128, 256, 0, stream>>>(z, zlin);     // 32768 chunks
    fused16_kernel<<<NG / EG, 512, 0, stream>>>(zlin, W, gamma, beta,
                                                convw, convb, out);
  } else {
    fused_decoder_kernel<<<(NG + 31) / 32, 256, 0, stream>>>(
        z, W, gamma, beta, convw, convb, out);
  }
}